// Round 6
// baseline (382.859 us; speedup 1.0000x reference)
//
#include <hip/hip_runtime.h>
#include <hip/hip_bf16.h>
#include <math.h>

// Problem constants
#define RM 13056         // 256*17*3 rows of flat x
#define KD 512           // feature dim
#define NE 2048          // codebook entries
#define NELEM 6684672.0  // 256*51*512 elements for the mean

// dist kernel tiling
#define BM 128
#define BN 128
#define BK 32
#define NKT (KD / BK)    // 16 k-tiles
#define NBLK (NE / BN)   // 16 n-blocks

typedef __attribute__((ext_vector_type(8))) short bf16x8;
typedef __attribute__((ext_vector_type(4))) float f32x4;
typedef unsigned long long ull;

// async global->LDS, 16B per lane; lds base wave-uniform, HW appends lane*16 (m104)
__device__ __forceinline__ void dma16(const void* g, void* l) {
  __builtin_amdgcn_global_load_lds((const __attribute__((address_space(1))) void*)g,
                                   (__attribute__((address_space(3))) void*)l, 16, 0, 0);
}

// order-preserving (dist, idx) -> u64 key: ascending u64 == lexicographic (d, ix)
__device__ __forceinline__ ull packdi(float d, int ix) {
  unsigned u = __float_as_uint(d);
  u ^= (unsigned)((int)u >> 31) | 0x80000000u;
  return ((ull)u << 32) | (unsigned)ix;
}

// ---------------------------------------------------------------------------
// K_prep: fused preprocessing.
//  blocks [0, XB): split X fp32 -> bf16 hi/lo in the k_dist DMA layout
//  blocks [XB, XB+EB): same for E
//  blocks [XB+EB, XB+EB+NB): E row norms (fp32)
//  block 0 also zeroes the 32B atomic header in ws.
#define XB (RM * 64 / 256)   // 3264
#define EB (NE * 64 / 256)   // 512
#define NB (NE / 4)          // 512
__device__ __forceinline__ void split_chunks(const float* __restrict__ src,
                                             unsigned short* __restrict__ hi,
                                             unsigned short* __restrict__ lo,
                                             int rows, int o) {
  int t4 = o >> 2;
  int kt = t4 / rows;
  int row = t4 - kt * rows;
  int slot = o & 3;
  int q = slot ^ ((row >> 1) & 3);
  const float* s = src + (size_t)row * KD + kt * 32 + q * 8;
  float4 v0 = ((const float4*)s)[0];
  float4 v1 = ((const float4*)s)[1];
  float f[8] = {v0.x, v0.y, v0.z, v0.w, v1.x, v1.y, v1.z, v1.w};
  unsigned hh[4], ll[4];
#pragma unroll
  for (int j = 0; j < 4; ++j) {
    __hip_bfloat16 b0 = __float2bfloat16(f[2 * j]);
    __hip_bfloat16 b1 = __float2bfloat16(f[2 * j + 1]);
    __hip_bfloat16 c0 = __float2bfloat16(f[2 * j] - __bfloat162float(b0));
    __hip_bfloat16 c1 = __float2bfloat16(f[2 * j + 1] - __bfloat162float(b1));
    hh[j] = (unsigned)*(unsigned short*)&b0 | ((unsigned)*(unsigned short*)&b1 << 16);
    ll[j] = (unsigned)*(unsigned short*)&c0 | ((unsigned)*(unsigned short*)&c1 << 16);
  }
  ((uint4*)hi)[o] = make_uint4(hh[0], hh[1], hh[2], hh[3]);
  ((uint4*)lo)[o] = make_uint4(ll[0], ll[1], ll[2], ll[3]);
}

__global__ __launch_bounds__(256) void k_prep(const float* __restrict__ X,
                                              const float* __restrict__ E,
                                              unsigned short* __restrict__ Xh,
                                              unsigned short* __restrict__ Xl,
                                              unsigned short* __restrict__ Eh,
                                              unsigned short* __restrict__ El,
                                              float* __restrict__ EN,
                                              ull* __restrict__ hdr) {
  const int b = blockIdx.x, tid = threadIdx.x;
  if (b == 0 && tid < 4) hdr[tid] = 0ull;  // S1, S3, counter, pad
  if (b < XB) {
    split_chunks(X, Xh, Xl, RM, b * 256 + tid);
  } else if (b < XB + EB) {
    split_chunks(E, Eh, El, NE, (b - XB) * 256 + tid);
  } else {
    int n = (b - XB - EB) * 4 + (tid >> 6);
    int lane = tid & 63;
    const float* e = E + (size_t)n * KD;
    float s = 0.f;
#pragma unroll
    for (int j = 0; j < 8; ++j) { float v = e[lane + 64 * j]; s += v * v; }
#pragma unroll
    for (int off = 32; off; off >>= 1) s += __shfl_down(s, off);
    if (lane == 0) EN[n] = s;
  }
}

// ---------------------------------------------------------------------------
// LDS chunk addressing (ushort elem offset): chunk q of local row at slot
// q ^ ((row>>1)&3). Same image as round 5 (conflicts measured 0).
__device__ __forceinline__ int chidx(int row, int q) {
  return (row * 4 + (q ^ ((row >> 1) & 3))) * 8;
}

// K1: split-bf16 MFMA distance tile, double-buffered LDS, ONE barrier per kt:
// [barrier: drains DMA(kt) issued a full compute-phase ago] ->
// [issue DMA(kt+1) -> other buf] -> [compute(kt)].
// grid (102,16), block 256 = 4 waves. Epilogue: per-thread top-4 + 4-round
// u64 min-extraction across the 16-lane group.
__global__ __launch_bounds__(256) void k_dist_bf16(
    const unsigned short* __restrict__ Xh, const unsigned short* __restrict__ Xl,
    const unsigned short* __restrict__ Eh, const unsigned short* __restrict__ El,
    const float* __restrict__ EN, ull* __restrict__ cand) {
  __shared__ __align__(16) unsigned short sXh[2][BM * BK], sXl[2][BM * BK];
  __shared__ __align__(16) unsigned short sEh[2][BN * BK], sEl[2][BN * BK];
  __shared__ float sEN[BN];

  const int tid = threadIdx.x;
  const int lane = tid & 63;
  const int w = tid >> 6;
  const int quad = lane >> 4;
  const int lx = lane & 15;
  const int rowBase = blockIdx.x * BM;
  const int colBase = blockIdx.y * BN;

  if (tid < BN) sEN[tid] = EN[colBase + tid];

  // frag LDS offsets (constant per lane)
  int aidx[2], bidx[8];
#pragma unroll
  for (int mt = 0; mt < 2; ++mt) aidx[mt] = chidx(w * 32 + mt * 16 + lx, quad);
#pragma unroll
  for (int ct = 0; ct < 8; ++ct) bidx[ct] = chidx(ct * 16 + lx, quad);

  f32x4 acc[2][8];
#pragma unroll
  for (int mt = 0; mt < 2; ++mt)
#pragma unroll
    for (int ct = 0; ct < 8; ++ct) acc[mt][ct] = (f32x4){0.f, 0.f, 0.f, 0.f};

  // prologue: stage kt=0 into buffer 0
  {
    const size_t xbase = (size_t)rowBase * 4;
    const size_t ebase = (size_t)colBase * 4;
#pragma unroll
    for (int i = 0; i < 2; ++i) {
      const int c = i * 256 + tid;
      const int ldsOff = (i * 256 + w * 64) * 8;
      dma16(Xh + (xbase + c) * 8, &sXh[0][ldsOff]);
      dma16(Xl + (xbase + c) * 8, &sXl[0][ldsOff]);
      dma16(Eh + (ebase + c) * 8, &sEh[0][ldsOff]);
      dma16(El + (ebase + c) * 8, &sEl[0][ldsOff]);
    }
  }

  for (int kt = 0; kt < NKT; ++kt) {
    const int cur = kt & 1;
    __syncthreads();  // drains DMA(kt) (in flight through compute(kt-1)); also
                      // guarantees buf cur^1's readers (iteration kt-1) done
    if (kt + 1 < NKT) {
      const int nxt = cur ^ 1;
      const size_t xbase = ((size_t)(kt + 1) * RM + rowBase) * 4;
      const size_t ebase = ((size_t)(kt + 1) * NE + colBase) * 4;
#pragma unroll
      for (int i = 0; i < 2; ++i) {
        const int c = i * 256 + tid;
        const int ldsOff = (i * 256 + w * 64) * 8;
        dma16(Xh + (xbase + c) * 8, &sXh[nxt][ldsOff]);
        dma16(Xl + (xbase + c) * 8, &sXl[nxt][ldsOff]);
        dma16(Eh + (ebase + c) * 8, &sEh[nxt][ldsOff]);
        dma16(El + (ebase + c) * 8, &sEl[nxt][ldsOff]);
      }
    }

    bf16x8 Ah[2], Al[2];
#pragma unroll
    for (int mt = 0; mt < 2; ++mt) {
      Ah[mt] = *(const bf16x8*)&sXh[cur][aidx[mt]];
      Al[mt] = *(const bf16x8*)&sXl[cur][aidx[mt]];
    }
#pragma unroll
    for (int ct = 0; ct < 8; ++ct) {
      bf16x8 Bh = *(const bf16x8*)&sEh[cur][bidx[ct]];
      bf16x8 Bl = *(const bf16x8*)&sEl[cur][bidx[ct]];
#pragma unroll
      for (int mt = 0; mt < 2; ++mt) {
        acc[mt][ct] = __builtin_amdgcn_mfma_f32_16x16x32_bf16(Ah[mt], Bh, acc[mt][ct], 0, 0, 0);
        acc[mt][ct] = __builtin_amdgcn_mfma_f32_16x16x32_bf16(Al[mt], Bh, acc[mt][ct], 0, 0, 0);
        acc[mt][ct] = __builtin_amdgcn_mfma_f32_16x16x32_bf16(Ah[mt], Bl, acc[mt][ct], 0, 0, 0);
      }
    }
  }

  // epilogue: C/D layout col=lane&15, row=quad*4+reg (m89/m91)
  float en[8];
#pragma unroll
  for (int ct = 0; ct < 8; ++ct) en[ct] = sEN[ct * 16 + lx];

#pragma unroll
  for (int mt = 0; mt < 2; ++mt) {
#pragma unroll
    for (int j = 0; j < 4; ++j) {
      float a0 = 3.4e38f, a1 = 3.4e38f, a2 = 3.4e38f, a3 = 3.4e38f;
      int i0 = 0x7fffffff, i1 = i0, i2 = i0, i3 = i0;
#pragma unroll
      for (int ct = 0; ct < 8; ++ct) {
        float d = en[ct] - 2.0f * acc[mt][ct][j];
        int ix = colBase + ct * 16 + lx;
        // ascending idx + strict < keeps the lower index on ties
        if (d < a3) {
          if (d < a2) { a3 = a2; i3 = i2;
            if (d < a1) { a2 = a1; i2 = i1;
              if (d < a0) { a1 = a0; i1 = i0; a0 = d; i0 = ix; }
              else { a1 = d; i1 = ix; } }
            else { a2 = d; i2 = ix; } }
          else { a3 = d; i3 = ix; }
        }
      }
      // 4-round min-extraction across the 16-lane group (keys unique per row)
      ull k0 = packdi(a0, i0), k1 = packdi(a1, i1);
      ull k2 = packdi(a2, i2), k3 = packdi(a3, i3);
      int pos = 0;
      ull res[4];
#pragma unroll
      for (int r = 0; r < 4; ++r) {
        ull h = pos == 0 ? k0 : pos == 1 ? k1 : pos == 2 ? k2 : pos == 3 ? k3 : ~0ull;
        ull m = h;
#pragma unroll
        for (int step = 1; step < 16; step <<= 1) {
          ull o = __shfl_xor(m, step, 16);
          m = o < m ? o : m;
        }
        res[r] = m;
        pos += (h == m) ? 1 : 0;
      }
      if (lx == 0) {
        int row = rowBase + w * 32 + mt * 16 + quad * 4 + j;
        ull* dst = cand + (size_t)row * (NBLK * 4) + blockIdx.y * 4;
        dst[0] = res[0]; dst[1] = res[1]; dst[2] = res[2]; dst[3] = res[3];
      }
    }
  }
}

// ---------------------------------------------------------------------------
// K1b: merge 64 candidates/row -> global top-8 indices (64-lane bitonic, u64).
__global__ __launch_bounds__(256) void k_merge(const ull* __restrict__ cand,
                                               int* __restrict__ top8) {
  const int lane = threadIdx.x & 63;
  const int row = blockIdx.x * 4 + (threadIdx.x >> 6);
  ull k = cand[(size_t)row * 64 + lane];
#pragma unroll
  for (int kk = 2; kk <= 64; kk <<= 1) {
#pragma unroll
    for (int j = kk >> 1; j > 0; j >>= 1) {
      ull o = __shfl_xor(k, j, 64);
      bool dirUp = (lane & kk) == 0;
      bool lower = (lane & j) == 0;
      bool pl = o < k;
      bool take = (dirUp == lower) ? pl : !pl;
      if (take) k = o;
    }
  }
  if (lane < 8) top8[(size_t)row * 8 + lane] = (int)(k & 0xffffffffull);
}

// ---------------------------------------------------------------------------
// K2: fp64 refinement (one wave per row) + fused global reduction/finalize.
// Per block: 4 rows' (S1,S3) summed, atomicAdd'd into hdr; last block
// computes cp_score & k_loss. hdr: [0]=S1, [1]=S3, [2]=counter (zeroed by k_prep).
__global__ __launch_bounds__(256) void k_refine(const float* __restrict__ X,
                                                const float* __restrict__ E,
                                                const int* __restrict__ top8,
                                                float* __restrict__ outF,
                                                double* __restrict__ hdrD,
                                                unsigned* __restrict__ hdrC,
                                                float* __restrict__ out,
                                                int nblocks) {
  const int w = threadIdx.x >> 6, lane = threadIdx.x & 63;
  const int row = blockIdx.x * 4 + w;
  __shared__ double bs1[4], bs3[4];
  const float* xr = X + (size_t)row * KD;
  float4 x0 = *(const float4*)(xr + lane * 8);
  float4 x1 = *(const float4*)(xr + lane * 8 + 4);
  int ci[8];
#pragma unroll
  for (int c = 0; c < 8; ++c) ci[c] = top8[(size_t)row * 8 + c];
  double a[8];
#pragma unroll
  for (int c = 0; c < 8; ++c) {
    const float* er = E + (size_t)ci[c] * KD;
    float4 e0 = *(const float4*)(er + lane * 8);
    float4 e1 = *(const float4*)(er + lane * 8 + 4);
    double s = 0.0;
    double d0 = (double)e0.x - (double)x0.x; s += d0 * d0;
    double d1 = (double)e0.y - (double)x0.y; s += d1 * d1;
    double d2 = (double)e0.z - (double)x0.z; s += d2 * d2;
    double d3 = (double)e0.w - (double)x0.w; s += d3 * d3;
    double d4 = (double)e1.x - (double)x1.x; s += d4 * d4;
    double d5 = (double)e1.y - (double)x1.y; s += d5 * d5;
    double d6 = (double)e1.z - (double)x1.z; s += d6 * d6;
    double d7 = (double)e1.w - (double)x1.w; s += d7 * d7;
    a[c] = s;
  }
#pragma unroll
  for (int c = 0; c < 8; ++c)
#pragma unroll
    for (int off = 32; off; off >>= 1) a[c] += __shfl_down(a[c], off);
  int best = 0;
  if (lane == 0) {
    double d[8]; int id[8];
#pragma unroll
    for (int c = 0; c < 8; ++c) { d[c] = a[c]; id[c] = ci[c]; }
    for (int i = 0; i < 8; ++i)
      for (int j = i + 1; j < 8; ++j)
        if (d[j] < d[i] || (d[j] == d[i] && id[j] < id[i])) {
          double dt = d[i]; d[i] = d[j]; d[j] = dt;
          int it = id[i]; id[i] = id[j]; id[j] = it;
        }
    bs1[w] = d[0];   // SSE to nearest
    bs3[w] = d[2];   // SSE to third
    best = id[0];
  }
  best = __shfl(best, 0);
  const float* er = E + (size_t)best * KD;
  *(float4*)(outF + (size_t)row * KD + lane * 8) = *(const float4*)(er + lane * 8);
  *(float4*)(outF + (size_t)row * KD + lane * 8 + 4) = *(const float4*)(er + lane * 8 + 4);
  __syncthreads();
  if (threadIdx.x == 0) {
    atomicAdd(&hdrD[0], bs1[0] + bs1[1] + bs1[2] + bs1[3]);
    atomicAdd(&hdrD[1], bs3[0] + bs3[1] + bs3[2] + bs3[3]);
    __threadfence();
    unsigned old = atomicAdd(hdrC, 1u);
    if (old == (unsigned)(nblocks - 1)) {
      double S1 = atomicAdd(&hdrD[0], 0.0);   // atomic read-after-all-adds
      double S3 = atomicAdd(&hdrD[1], 0.0);
      out[0] = (float)(1.0 - sqrt(S1 / S3));  // cp_score
      out[1] = (float)(0.25 * S1 / NELEM);    // k_loss
    }
  }
}

// ---------------------------------------------------------------------------
extern "C" void kernel_launch(void* const* d_in, const int* in_sizes, int n_in,
                              void* d_out, int out_size, void* d_ws, size_t ws_size,
                              hipStream_t stream) {
  const float* IP = (const float*)d_in[0];   // (256,51,512) fp32
  const float* EMB = (const float*)d_in[1];  // (2048,512) fp32
  float* out = (float*)d_out;

  // d_out tail doubles as candidate scratch (overwritten later by k_refine):
  // 13056 rows x 64 u64 = 6.68 MB <= out capacity 26.7 MB. (out+2 is 8B-aligned.)
  ull* cand = (ull*)(out + 2);

  // ws layout (16B-aligned): hdr | EN | top8 | Xh | Xl | Eh | El  (~30 MiB)
  char* ws = (char*)d_ws;
  size_t off = 0;
  ull* hdr = (ull*)(ws);                 off += 32;   // S1,S3 (dbl) + counter
  float* EN = (float*)(ws + off);        off += NE * 4;
  int* top8 = (int*)(ws + off);          off += (size_t)RM * 8 * 4;
  unsigned short* Xh = (unsigned short*)(ws + off); off += (size_t)RM * KD * 2;
  unsigned short* Xl = (unsigned short*)(ws + off); off += (size_t)RM * KD * 2;
  unsigned short* Ehs = (unsigned short*)(ws + off); off += (size_t)NE * KD * 2;
  unsigned short* Els = (unsigned short*)(ws + off); off += (size_t)NE * KD * 2;

  hipLaunchKernelGGL(k_prep, dim3(XB + EB + NB), dim3(256), 0, stream,
                     IP, EMB, Xh, Xl, Ehs, Els, EN, hdr);
  hipLaunchKernelGGL(k_dist_bf16, dim3(RM / BM, NBLK), dim3(256), 0, stream,
                     Xh, Xl, Ehs, Els, EN, cand);
  hipLaunchKernelGGL(k_merge, dim3(RM / 4), dim3(256), 0, stream, cand, top8);
  hipLaunchKernelGGL(k_refine, dim3(RM / 4), dim3(256), 0, stream,
                     IP, EMB, top8, out + 2, (double*)hdr, (unsigned*)(hdr + 2),
                     out, RM / 4);
}

// Round 7
// 351.865 us; speedup vs baseline: 1.0881x; 1.0881x over previous
//
#include <hip/hip_runtime.h>
#include <hip/hip_bf16.h>
#include <math.h>

// Problem constants
#define RM 13056         // 256*17*3 rows of flat x
#define KD 512           // feature dim
#define NE 2048          // codebook entries
#define NELEM 6684672.0  // 256*51*512 elements for the mean

// dist kernel tiling
#define BM 128
#define BN 128
#define BK 32
#define NKT (KD / BK)    // 16 k-tiles
#define NBLK (NE / BN)   // 16 n-blocks

typedef __attribute__((ext_vector_type(8))) short bf16x8;
typedef __attribute__((ext_vector_type(4))) float f32x4;
typedef unsigned long long ull;

// async global->LDS, 16B per lane; lds base wave-uniform, HW appends lane*16 (m104)
__device__ __forceinline__ void dma16(const void* g, void* l) {
  __builtin_amdgcn_global_load_lds((const __attribute__((address_space(1))) void*)g,
                                   (__attribute__((address_space(3))) void*)l, 16, 0, 0);
}

// order-preserving (dist, idx) -> u64 key: ascending u64 == lexicographic (d, ix)
__device__ __forceinline__ ull packdi(float d, int ix) {
  unsigned u = __float_as_uint(d);
  u ^= (unsigned)((int)u >> 31) | 0x80000000u;
  return ((ull)u << 32) | (unsigned)ix;
}

// ---------------------------------------------------------------------------
// K_prep: fused preprocessing.
//  blocks [0, XB): split X fp32 -> bf16 hi/lo in the k_dist DMA layout
//  blocks [XB, XB+EB): same for E
//  blocks [XB+EB, XB+EB+NB): E row norms (fp32)
//  block 0 also zeroes the 8 KB atomic header in ws.
#define XB (RM * 64 / 256)   // 3264
#define EB (NE * 64 / 256)   // 512
#define NB (NE / 4)          // 512
__device__ __forceinline__ void split_chunks(const float* __restrict__ src,
                                             unsigned short* __restrict__ hi,
                                             unsigned short* __restrict__ lo,
                                             int rows, int o) {
  int t4 = o >> 2;
  int kt = t4 / rows;
  int row = t4 - kt * rows;
  int slot = o & 3;
  int q = slot ^ ((row >> 1) & 3);
  const float* s = src + (size_t)row * KD + kt * 32 + q * 8;
  float4 v0 = ((const float4*)s)[0];
  float4 v1 = ((const float4*)s)[1];
  float f[8] = {v0.x, v0.y, v0.z, v0.w, v1.x, v1.y, v1.z, v1.w};
  unsigned hh[4], ll[4];
#pragma unroll
  for (int j = 0; j < 4; ++j) {
    __hip_bfloat16 b0 = __float2bfloat16(f[2 * j]);
    __hip_bfloat16 b1 = __float2bfloat16(f[2 * j + 1]);
    __hip_bfloat16 c0 = __float2bfloat16(f[2 * j] - __bfloat162float(b0));
    __hip_bfloat16 c1 = __float2bfloat16(f[2 * j + 1] - __bfloat162float(b1));
    hh[j] = (unsigned)*(unsigned short*)&b0 | ((unsigned)*(unsigned short*)&b1 << 16);
    ll[j] = (unsigned)*(unsigned short*)&c0 | ((unsigned)*(unsigned short*)&c1 << 16);
  }
  ((uint4*)hi)[o] = make_uint4(hh[0], hh[1], hh[2], hh[3]);
  ((uint4*)lo)[o] = make_uint4(ll[0], ll[1], ll[2], ll[3]);
}

__global__ __launch_bounds__(256) void k_prep(const float* __restrict__ X,
                                              const float* __restrict__ E,
                                              unsigned short* __restrict__ Xh,
                                              unsigned short* __restrict__ Xl,
                                              unsigned short* __restrict__ Eh,
                                              unsigned short* __restrict__ El,
                                              float* __restrict__ EN,
                                              ull* __restrict__ hdr) {
  const int b = blockIdx.x, tid = threadIdx.x;
  if (b == 0) {
    for (int i = tid; i < 1024; i += 256) hdr[i] = 0ull;  // 8 KB header
  }
  if (b < XB) {
    split_chunks(X, Xh, Xl, RM, b * 256 + tid);
  } else if (b < XB + EB) {
    split_chunks(E, Eh, El, NE, (b - XB) * 256 + tid);
  } else {
    int n = (b - XB - EB) * 4 + (tid >> 6);
    int lane = tid & 63;
    const float* e = E + (size_t)n * KD;
    float s = 0.f;
#pragma unroll
    for (int j = 0; j < 8; ++j) { float v = e[lane + 64 * j]; s += v * v; }
#pragma unroll
    for (int off = 32; off; off >>= 1) s += __shfl_down(s, off);
    if (lane == 0) EN[n] = s;
  }
}

// ---------------------------------------------------------------------------
// LDS chunk addressing (ushort elem offset): chunk q of local row at slot
// q ^ ((row>>1)&3). Conflicts measured 0 (rounds 4-6).
__device__ __forceinline__ int chidx(int row, int q) {
  return (row * 4 + (q ^ ((row >> 1) & 3))) * 8;
}

// K1: split-bf16 MFMA distance tile + per-row top-4 within this n-block.
// Round-5 single-buffer version verbatim (measured 131 us; dbuf was neutral).
__global__ __launch_bounds__(256) void k_dist_bf16(
    const unsigned short* __restrict__ Xh, const unsigned short* __restrict__ Xl,
    const unsigned short* __restrict__ Eh, const unsigned short* __restrict__ El,
    const float* __restrict__ EN, ull* __restrict__ cand) {
  __shared__ __align__(16) unsigned short sXh[BM * BK], sXl[BM * BK];
  __shared__ __align__(16) unsigned short sEh[BN * BK], sEl[BN * BK];
  __shared__ float sEN[BN];

  const int tid = threadIdx.x;
  const int lane = tid & 63;
  const int w = tid >> 6;
  const int quad = lane >> 4;
  const int lx = lane & 15;
  const int rowBase = blockIdx.x * BM;
  const int colBase = blockIdx.y * BN;

  if (tid < BN) sEN[tid] = EN[colBase + tid];

  // frag LDS offsets (constant per lane)
  int aidx[2], bidx[8];
#pragma unroll
  for (int mt = 0; mt < 2; ++mt) aidx[mt] = chidx(w * 32 + mt * 16 + lx, quad);
#pragma unroll
  for (int ct = 0; ct < 8; ++ct) bidx[ct] = chidx(ct * 16 + lx, quad);

  f32x4 acc[2][8];
#pragma unroll
  for (int mt = 0; mt < 2; ++mt)
#pragma unroll
    for (int ct = 0; ct < 8; ++ct) acc[mt][ct] = (f32x4){0.f, 0.f, 0.f, 0.f};

  for (int kt = 0; kt < NKT; ++kt) {
    const size_t xbase = ((size_t)kt * RM + rowBase) * 4;
    const size_t ebase = ((size_t)kt * NE + colBase) * 4;
    __syncthreads();  // previous tile's readers done
#pragma unroll
    for (int i = 0; i < 2; ++i) {
      const int c = i * 256 + tid;                   // chunk within tile
      const int ldsOff = (i * 256 + w * 64) * 8;     // wave-uniform LDS base
      dma16(Xh + (xbase + c) * 8, &sXh[ldsOff]);
      dma16(Xl + (xbase + c) * 8, &sXl[ldsOff]);
      dma16(Eh + (ebase + c) * 8, &sEh[ldsOff]);
      dma16(El + (ebase + c) * 8, &sEl[ldsOff]);
    }
    __syncthreads();  // compiler drains vmcnt before barrier

    bf16x8 Ah[2], Al[2];
#pragma unroll
    for (int mt = 0; mt < 2; ++mt) {
      Ah[mt] = *(const bf16x8*)&sXh[aidx[mt]];
      Al[mt] = *(const bf16x8*)&sXl[aidx[mt]];
    }
#pragma unroll
    for (int ct = 0; ct < 8; ++ct) {
      bf16x8 Bh = *(const bf16x8*)&sEh[bidx[ct]];
      bf16x8 Bl = *(const bf16x8*)&sEl[bidx[ct]];
#pragma unroll
      for (int mt = 0; mt < 2; ++mt) {
        acc[mt][ct] = __builtin_amdgcn_mfma_f32_16x16x32_bf16(Ah[mt], Bh, acc[mt][ct], 0, 0, 0);
        acc[mt][ct] = __builtin_amdgcn_mfma_f32_16x16x32_bf16(Al[mt], Bh, acc[mt][ct], 0, 0, 0);
        acc[mt][ct] = __builtin_amdgcn_mfma_f32_16x16x32_bf16(Ah[mt], Bl, acc[mt][ct], 0, 0, 0);
      }
    }
  }

  // epilogue: C/D layout col=lane&15, row=quad*4+reg (m89/m91)
  float en[8];
#pragma unroll
  for (int ct = 0; ct < 8; ++ct) en[ct] = sEN[ct * 16 + lx];

#pragma unroll
  for (int mt = 0; mt < 2; ++mt) {
#pragma unroll
    for (int j = 0; j < 4; ++j) {
      float a0 = 3.4e38f, a1 = 3.4e38f, a2 = 3.4e38f, a3 = 3.4e38f;
      int i0 = 0x7fffffff, i1 = i0, i2 = i0, i3 = i0;
#pragma unroll
      for (int ct = 0; ct < 8; ++ct) {
        float d = en[ct] - 2.0f * acc[mt][ct][j];
        int ix = colBase + ct * 16 + lx;
        // ascending idx + strict < keeps the lower index on ties
        if (d < a3) {
          if (d < a2) { a3 = a2; i3 = i2;
            if (d < a1) { a2 = a1; i2 = i1;
              if (d < a0) { a1 = a0; i1 = i0; a0 = d; i0 = ix; }
              else { a1 = d; i1 = ix; } }
            else { a2 = d; i2 = ix; } }
          else { a3 = d; i3 = ix; }
        }
      }
      // 4-round min-extraction across the 16-lane group (keys unique per row)
      ull k0 = packdi(a0, i0), k1 = packdi(a1, i1);
      ull k2 = packdi(a2, i2), k3 = packdi(a3, i3);
      int pos = 0;
      ull res[4];
#pragma unroll
      for (int r = 0; r < 4; ++r) {
        ull h = pos == 0 ? k0 : pos == 1 ? k1 : pos == 2 ? k2 : pos == 3 ? k3 : ~0ull;
        ull m = h;
#pragma unroll
        for (int step = 1; step < 16; step <<= 1) {
          ull o = __shfl_xor(m, step, 16);
          m = o < m ? o : m;
        }
        res[r] = m;
        pos += (h == m) ? 1 : 0;
      }
      if (lx == 0) {
        int row = rowBase + w * 32 + mt * 16 + quad * 4 + j;
        ull* dst = cand + (size_t)row * (NBLK * 4) + blockIdx.y * 4;
        dst[0] = res[0]; dst[1] = res[1]; dst[2] = res[2]; dst[3] = res[3];
      }
    }
  }
}

// ---------------------------------------------------------------------------
// Shared tail core: fp64 refine of ci[8] for `row` (one wave), then spread-slot
// partial accumulation + last-block finalize.
// hdrD: 64 slots spaced 64 B apart (slot s -> hdrD[8s]=S1, hdrD[8s+1]=S3);
// counter u32 at hdrD+512.
__device__ __forceinline__ void refine_core(const float* __restrict__ X,
                                            const float* __restrict__ E,
                                            const int* ci, int row,
                                            float* __restrict__ outF,
                                            double* __restrict__ hdrD,
                                            unsigned* __restrict__ hdrC,
                                            float* __restrict__ out, int nblocks) {
  const int w = threadIdx.x >> 6, lane = threadIdx.x & 63;
  __shared__ double bs1[4], bs3[4];
  __shared__ int isLast;
  const float* xr = X + (size_t)row * KD;
  float4 x0 = *(const float4*)(xr + lane * 8);
  float4 x1 = *(const float4*)(xr + lane * 8 + 4);
  double a[8];
#pragma unroll
  for (int c = 0; c < 8; ++c) {
    const float* er = E + (size_t)ci[c] * KD;
    float4 e0 = *(const float4*)(er + lane * 8);
    float4 e1 = *(const float4*)(er + lane * 8 + 4);
    double s = 0.0;
    double d0 = (double)e0.x - (double)x0.x; s += d0 * d0;
    double d1 = (double)e0.y - (double)x0.y; s += d1 * d1;
    double d2 = (double)e0.z - (double)x0.z; s += d2 * d2;
    double d3 = (double)e0.w - (double)x0.w; s += d3 * d3;
    double d4 = (double)e1.x - (double)x1.x; s += d4 * d4;
    double d5 = (double)e1.y - (double)x1.y; s += d5 * d5;
    double d6 = (double)e1.z - (double)x1.z; s += d6 * d6;
    double d7 = (double)e1.w - (double)x1.w; s += d7 * d7;
    a[c] = s;
  }
#pragma unroll
  for (int c = 0; c < 8; ++c)
#pragma unroll
    for (int off = 32; off; off >>= 1) a[c] += __shfl_down(a[c], off);
  int best = 0;
  if (lane == 0) {
    double d[8]; int id[8];
#pragma unroll
    for (int c = 0; c < 8; ++c) { d[c] = a[c]; id[c] = ci[c]; }
    for (int i = 0; i < 8; ++i)
      for (int j = i + 1; j < 8; ++j)
        if (d[j] < d[i] || (d[j] == d[i] && id[j] < id[i])) {
          double dt = d[i]; d[i] = d[j]; d[j] = dt;
          int it = id[i]; id[i] = id[j]; id[j] = it;
        }
    bs1[w] = d[0];   // SSE to nearest
    bs3[w] = d[2];   // SSE to third
    best = id[0];
  }
  best = __shfl(best, 0);
  const float* er = E + (size_t)best * KD;
  *(float4*)(outF + (size_t)row * KD + lane * 8) = *(const float4*)(er + lane * 8);
  *(float4*)(outF + (size_t)row * KD + lane * 8 + 4) = *(const float4*)(er + lane * 8 + 4);
  __syncthreads();
  if (threadIdx.x == 0) {
    const int slot = blockIdx.x & 63;       // 64 slots, 64 B apart: ~51 adds/slot
    atomicAdd(&hdrD[slot * 8], bs1[0] + bs1[1] + bs1[2] + bs1[3]);
    atomicAdd(&hdrD[slot * 8 + 1], bs3[0] + bs3[1] + bs3[2] + bs3[3]);
    __threadfence();
    unsigned old = atomicAdd(hdrC, 1u);
    isLast = (old == (unsigned)(nblocks - 1)) ? 1 : 0;
  }
  __syncthreads();
  if (isLast) {
    __threadfence();
    // wave0 sums the 64 S1 slots, wave1 the 64 S3 slots (agent-scope loads)
    double v = 0.0;
    if (w < 2) v = __hip_atomic_load(&hdrD[lane * 8 + w], __ATOMIC_RELAXED,
                                     __HIP_MEMORY_SCOPE_AGENT);
#pragma unroll
    for (int off = 32; off; off >>= 1) v += __shfl_down(v, off);
    __shared__ double sS[2];
    if (lane == 0 && w < 2) sS[w] = v;
    __syncthreads();
    if (threadIdx.x == 0) {
      double S1 = sS[0], S3 = sS[1];
      out[0] = (float)(1.0 - sqrt(S1 / S3));  // cp_score
      out[1] = (float)(0.25 * S1 / NELEM);    // k_loss
    }
  }
}

// ---------------------------------------------------------------------------
// Fused merge+refine+finalize (cand in ws; no overwrite hazard with outF).
__global__ __launch_bounds__(256) void k_mrf(const float* __restrict__ X,
                                             const float* __restrict__ E,
                                             const ull* __restrict__ cand,
                                             float* __restrict__ outF,
                                             double* __restrict__ hdrD,
                                             unsigned* __restrict__ hdrC,
                                             float* __restrict__ out, int nblocks) {
  const int lane = threadIdx.x & 63;
  const int row = blockIdx.x * 4 + (threadIdx.x >> 6);
  ull k = cand[(size_t)row * 64 + lane];
#pragma unroll
  for (int kk = 2; kk <= 64; kk <<= 1) {
#pragma unroll
    for (int j = kk >> 1; j > 0; j >>= 1) {
      ull o = __shfl_xor(k, j, 64);
      bool dirUp = (lane & kk) == 0;
      bool lower = (lane & j) == 0;
      bool pl = o < k;
      bool take = (dirUp == lower) ? pl : !pl;
      if (take) k = o;
    }
  }
  int ci[8];
#pragma unroll
  for (int c = 0; c < 8; ++c) ci[c] = (int)(__shfl(k, c, 64) & 0xffffffffull);
  refine_core(X, E, ci, row, outF, hdrD, hdrC, out, nblocks);
}

// ---------------------------------------------------------------------------
// Fallback pair (cand in d_out tail): separate merge, then refine+finalize.
__global__ __launch_bounds__(256) void k_merge(const ull* __restrict__ cand,
                                               int* __restrict__ top8) {
  const int lane = threadIdx.x & 63;
  const int row = blockIdx.x * 4 + (threadIdx.x >> 6);
  ull k = cand[(size_t)row * 64 + lane];
#pragma unroll
  for (int kk = 2; kk <= 64; kk <<= 1) {
#pragma unroll
    for (int j = kk >> 1; j > 0; j >>= 1) {
      ull o = __shfl_xor(k, j, 64);
      bool dirUp = (lane & kk) == 0;
      bool lower = (lane & j) == 0;
      bool pl = o < k;
      bool take = (dirUp == lower) ? pl : !pl;
      if (take) k = o;
    }
  }
  if (lane < 8) top8[(size_t)row * 8 + lane] = (int)(k & 0xffffffffull);
}

__global__ __launch_bounds__(256) void k_refine_fb(const float* __restrict__ X,
                                                   const float* __restrict__ E,
                                                   const int* __restrict__ top8,
                                                   float* __restrict__ outF,
                                                   double* __restrict__ hdrD,
                                                   unsigned* __restrict__ hdrC,
                                                   float* __restrict__ out, int nblocks) {
  const int row = blockIdx.x * 4 + (threadIdx.x >> 6);
  int ci[8];
#pragma unroll
  for (int c = 0; c < 8; ++c) ci[c] = top8[(size_t)row * 8 + c];
  refine_core(X, E, ci, row, outF, hdrD, hdrC, out, nblocks);
}

// ---------------------------------------------------------------------------
extern "C" void kernel_launch(void* const* d_in, const int* in_sizes, int n_in,
                              void* d_out, int out_size, void* d_ws, size_t ws_size,
                              hipStream_t stream) {
  const float* IP = (const float*)d_in[0];   // (256,51,512) fp32
  const float* EMB = (const float*)d_in[1];  // (2048,512) fp32
  float* out = (float*)d_out;

  // ws layout (16B-aligned): hdr(8KB) | EN | top8 | Xh | Xl | Eh | El [| cand]
  char* ws = (char*)d_ws;
  size_t off = 0;
  ull* hdr = (ull*)(ws);                 off += 8192;   // 64 spread slots + counter
  float* EN = (float*)(ws + off);        off += NE * 4;
  int* top8 = (int*)(ws + off);          off += (size_t)RM * 8 * 4;
  unsigned short* Xh = (unsigned short*)(ws + off); off += (size_t)RM * KD * 2;
  unsigned short* Xl = (unsigned short*)(ws + off); off += (size_t)RM * KD * 2;
  unsigned short* Ehs = (unsigned short*)(ws + off); off += (size_t)NE * KD * 2;
  unsigned short* Els = (unsigned short*)(ws + off); off += (size_t)NE * KD * 2;
  ull* candWs = (ull*)(ws + off);        off += (size_t)RM * 64 * 8;  // +6.7 MB
  const bool fused = ws_size >= off;     // ~37 MiB for the fused path

  double* hdrD = (double*)hdr;
  unsigned* hdrC = (unsigned*)(hdrD + 512);
  // fallback: cand lives in d_out tail (consumed by k_merge before outF writes)
  ull* cand = fused ? candWs : (ull*)(out + 2);

  hipLaunchKernelGGL(k_prep, dim3(XB + EB + NB), dim3(256), 0, stream,
                     IP, EMB, Xh, Xl, Ehs, Els, EN, hdr);
  hipLaunchKernelGGL(k_dist_bf16, dim3(RM / BM, NBLK), dim3(256), 0, stream,
                     Xh, Xl, Ehs, Els, EN, cand);
  if (fused) {
    hipLaunchKernelGGL(k_mrf, dim3(RM / 4), dim3(256), 0, stream,
                       IP, EMB, cand, out + 2, hdrD, hdrC, out, RM / 4);
  } else {
    hipLaunchKernelGGL(k_merge, dim3(RM / 4), dim3(256), 0, stream, cand, top8);
    hipLaunchKernelGGL(k_refine_fb, dim3(RM / 4), dim3(256), 0, stream,
                       IP, EMB, top8, out + 2, hdrD, hdrC, out, RM / 4);
  }
}

// Round 8
// 245.295 us; speedup vs baseline: 1.5608x; 1.4345x over previous
//
#include <hip/hip_runtime.h>
#include <hip/hip_bf16.h>
#include <math.h>

// Problem constants
#define RM 13056         // 256*17*3 rows of flat x
#define KD 512           // feature dim
#define NE 2048          // codebook entries
#define NELEM 6684672.0  // 256*51*512 elements for the mean

// dist kernel tiling
#define BM 128
#define BN 128
#define BK 32
#define NKT (KD / BK)    // 16 k-tiles
#define NBLK (NE / BN)   // 16 n-blocks
#define NTAIL (RM / 4)   // 3264 tail blocks (4 rows each)

typedef __attribute__((ext_vector_type(8))) short bf16x8;
typedef __attribute__((ext_vector_type(4))) float f32x4;
typedef unsigned long long ull;

// async global->LDS, 16B per lane; lds base wave-uniform, HW appends lane*16 (m104)
__device__ __forceinline__ void dma16(const void* g, void* l) {
  __builtin_amdgcn_global_load_lds((const __attribute__((address_space(1))) void*)g,
                                   (__attribute__((address_space(3))) void*)l, 16, 0, 0);
}

// order-preserving (dist, idx) -> u64 key: ascending u64 == lexicographic (d, ix)
__device__ __forceinline__ ull packdi(float d, int ix) {
  unsigned u = __float_as_uint(d);
  u ^= (unsigned)((int)u >> 31) | 0x80000000u;
  return ((ull)u << 32) | (unsigned)ix;
}

// ---------------------------------------------------------------------------
// K_prep: fused preprocessing.
//  blocks [0, XB): split X fp32 -> bf16 hi/lo in the k_dist DMA layout
//  blocks [XB, XB+EB): same for E
//  blocks [XB+EB, XB+EB+NB): E row norms (fp32)
#define XB (RM * 64 / 256)   // 3264
#define EB (NE * 64 / 256)   // 512
#define NB (NE / 4)          // 512
__device__ __forceinline__ void split_chunks(const float* __restrict__ src,
                                             unsigned short* __restrict__ hi,
                                             unsigned short* __restrict__ lo,
                                             int rows, int o) {
  int t4 = o >> 2;
  int kt = t4 / rows;
  int row = t4 - kt * rows;
  int slot = o & 3;
  int q = slot ^ ((row >> 1) & 3);
  const float* s = src + (size_t)row * KD + kt * 32 + q * 8;
  float4 v0 = ((const float4*)s)[0];
  float4 v1 = ((const float4*)s)[1];
  float f[8] = {v0.x, v0.y, v0.z, v0.w, v1.x, v1.y, v1.z, v1.w};
  unsigned hh[4], ll[4];
#pragma unroll
  for (int j = 0; j < 4; ++j) {
    __hip_bfloat16 b0 = __float2bfloat16(f[2 * j]);
    __hip_bfloat16 b1 = __float2bfloat16(f[2 * j + 1]);
    __hip_bfloat16 c0 = __float2bfloat16(f[2 * j] - __bfloat162float(b0));
    __hip_bfloat16 c1 = __float2bfloat16(f[2 * j + 1] - __bfloat162float(b1));
    hh[j] = (unsigned)*(unsigned short*)&b0 | ((unsigned)*(unsigned short*)&b1 << 16);
    ll[j] = (unsigned)*(unsigned short*)&c0 | ((unsigned)*(unsigned short*)&c1 << 16);
  }
  ((uint4*)hi)[o] = make_uint4(hh[0], hh[1], hh[2], hh[3]);
  ((uint4*)lo)[o] = make_uint4(ll[0], ll[1], ll[2], ll[3]);
}

__global__ __launch_bounds__(256) void k_prep(const float* __restrict__ X,
                                              const float* __restrict__ E,
                                              unsigned short* __restrict__ Xh,
                                              unsigned short* __restrict__ Xl,
                                              unsigned short* __restrict__ Eh,
                                              unsigned short* __restrict__ El,
                                              float* __restrict__ EN) {
  const int b = blockIdx.x, tid = threadIdx.x;
  if (b < XB) {
    split_chunks(X, Xh, Xl, RM, b * 256 + tid);
  } else if (b < XB + EB) {
    split_chunks(E, Eh, El, NE, (b - XB) * 256 + tid);
  } else {
    int n = (b - XB - EB) * 4 + (tid >> 6);
    int lane = tid & 63;
    const float* e = E + (size_t)n * KD;
    float s = 0.f;
#pragma unroll
    for (int j = 0; j < 8; ++j) { float v = e[lane + 64 * j]; s += v * v; }
#pragma unroll
    for (int off = 32; off; off >>= 1) s += __shfl_down(s, off);
    if (lane == 0) EN[n] = s;
  }
}

// ---------------------------------------------------------------------------
// LDS chunk addressing (ushort elem offset): chunk q of local row at slot
// q ^ ((row>>1)&3). Conflicts measured 0 (rounds 4-7).
__device__ __forceinline__ int chidx(int row, int q) {
  return (row * 4 + (q ^ ((row >> 1) & 3))) * 8;
}

// K1: split-bf16 MFMA distance tile + per-row top-4 within this n-block.
// Measured 131 us (round 5), conflicts 0. Unchanged.
__global__ __launch_bounds__(256) void k_dist_bf16(
    const unsigned short* __restrict__ Xh, const unsigned short* __restrict__ Xl,
    const unsigned short* __restrict__ Eh, const unsigned short* __restrict__ El,
    const float* __restrict__ EN, ull* __restrict__ cand) {
  __shared__ __align__(16) unsigned short sXh[BM * BK], sXl[BM * BK];
  __shared__ __align__(16) unsigned short sEh[BN * BK], sEl[BN * BK];
  __shared__ float sEN[BN];

  const int tid = threadIdx.x;
  const int lane = tid & 63;
  const int w = tid >> 6;
  const int quad = lane >> 4;
  const int lx = lane & 15;
  const int rowBase = blockIdx.x * BM;
  const int colBase = blockIdx.y * BN;

  if (tid < BN) sEN[tid] = EN[colBase + tid];

  // frag LDS offsets (constant per lane)
  int aidx[2], bidx[8];
#pragma unroll
  for (int mt = 0; mt < 2; ++mt) aidx[mt] = chidx(w * 32 + mt * 16 + lx, quad);
#pragma unroll
  for (int ct = 0; ct < 8; ++ct) bidx[ct] = chidx(ct * 16 + lx, quad);

  f32x4 acc[2][8];
#pragma unroll
  for (int mt = 0; mt < 2; ++mt)
#pragma unroll
    for (int ct = 0; ct < 8; ++ct) acc[mt][ct] = (f32x4){0.f, 0.f, 0.f, 0.f};

  for (int kt = 0; kt < NKT; ++kt) {
    const size_t xbase = ((size_t)kt * RM + rowBase) * 4;
    const size_t ebase = ((size_t)kt * NE + colBase) * 4;
    __syncthreads();  // previous tile's readers done
#pragma unroll
    for (int i = 0; i < 2; ++i) {
      const int c = i * 256 + tid;                   // chunk within tile
      const int ldsOff = (i * 256 + w * 64) * 8;     // wave-uniform LDS base
      dma16(Xh + (xbase + c) * 8, &sXh[ldsOff]);
      dma16(Xl + (xbase + c) * 8, &sXl[ldsOff]);
      dma16(Eh + (ebase + c) * 8, &sEh[ldsOff]);
      dma16(El + (ebase + c) * 8, &sEl[ldsOff]);
    }
    __syncthreads();  // compiler drains vmcnt before barrier

    bf16x8 Ah[2], Al[2];
#pragma unroll
    for (int mt = 0; mt < 2; ++mt) {
      Ah[mt] = *(const bf16x8*)&sXh[aidx[mt]];
      Al[mt] = *(const bf16x8*)&sXl[aidx[mt]];
    }
#pragma unroll
    for (int ct = 0; ct < 8; ++ct) {
      bf16x8 Bh = *(const bf16x8*)&sEh[bidx[ct]];
      bf16x8 Bl = *(const bf16x8*)&sEl[bidx[ct]];
#pragma unroll
      for (int mt = 0; mt < 2; ++mt) {
        acc[mt][ct] = __builtin_amdgcn_mfma_f32_16x16x32_bf16(Ah[mt], Bh, acc[mt][ct], 0, 0, 0);
        acc[mt][ct] = __builtin_amdgcn_mfma_f32_16x16x32_bf16(Al[mt], Bh, acc[mt][ct], 0, 0, 0);
        acc[mt][ct] = __builtin_amdgcn_mfma_f32_16x16x32_bf16(Ah[mt], Bl, acc[mt][ct], 0, 0, 0);
      }
    }
  }

  // epilogue: C/D layout col=lane&15, row=quad*4+reg (m89/m91)
  float en[8];
#pragma unroll
  for (int ct = 0; ct < 8; ++ct) en[ct] = sEN[ct * 16 + lx];

#pragma unroll
  for (int mt = 0; mt < 2; ++mt) {
#pragma unroll
    for (int j = 0; j < 4; ++j) {
      float a0 = 3.4e38f, a1 = 3.4e38f, a2 = 3.4e38f, a3 = 3.4e38f;
      int i0 = 0x7fffffff, i1 = i0, i2 = i0, i3 = i0;
#pragma unroll
      for (int ct = 0; ct < 8; ++ct) {
        float d = en[ct] - 2.0f * acc[mt][ct][j];
        int ix = colBase + ct * 16 + lx;
        // ascending idx + strict < keeps the lower index on ties
        if (d < a3) {
          if (d < a2) { a3 = a2; i3 = i2;
            if (d < a1) { a2 = a1; i2 = i1;
              if (d < a0) { a1 = a0; i1 = i0; a0 = d; i0 = ix; }
              else { a1 = d; i1 = ix; } }
            else { a2 = d; i2 = ix; } }
          else { a3 = d; i3 = ix; }
        }
      }
      // 4-round min-extraction across the 16-lane group (keys unique per row)
      ull k0 = packdi(a0, i0), k1 = packdi(a1, i1);
      ull k2 = packdi(a2, i2), k3 = packdi(a3, i3);
      int pos = 0;
      ull res[4];
#pragma unroll
      for (int r = 0; r < 4; ++r) {
        ull h = pos == 0 ? k0 : pos == 1 ? k1 : pos == 2 ? k2 : pos == 3 ? k3 : ~0ull;
        ull m = h;
#pragma unroll
        for (int step = 1; step < 16; step <<= 1) {
          ull o = __shfl_xor(m, step, 16);
          m = o < m ? o : m;
        }
        res[r] = m;
        pos += (h == m) ? 1 : 0;
      }
      if (lx == 0) {
        int row = rowBase + w * 32 + mt * 16 + quad * 4 + j;
        ull* dst = cand + (size_t)row * (NBLK * 4) + blockIdx.y * 4;
        dst[0] = res[0]; dst[1] = res[1]; dst[2] = res[2]; dst[3] = res[3];
      }
    }
  }
}

// ---------------------------------------------------------------------------
// Shared tail core: fp64 refine of ci[8] for `row` (one wave), then exact
// per-block (S1,S3) partials via PLAIN stores (no atomics, no fences).
__device__ __forceinline__ void refine_core(const float* __restrict__ X,
                                            const float* __restrict__ E,
                                            const int* ci, int row,
                                            float* __restrict__ outF,
                                            double* __restrict__ part) {
  const int w = threadIdx.x >> 6, lane = threadIdx.x & 63;
  __shared__ double bs1[4], bs3[4];
  const float* xr = X + (size_t)row * KD;
  float4 x0 = *(const float4*)(xr + lane * 8);
  float4 x1 = *(const float4*)(xr + lane * 8 + 4);
  double a[8];
#pragma unroll
  for (int c = 0; c < 8; ++c) {
    const float* er = E + (size_t)ci[c] * KD;
    float4 e0 = *(const float4*)(er + lane * 8);
    float4 e1 = *(const float4*)(er + lane * 8 + 4);
    double s = 0.0;
    double d0 = (double)e0.x - (double)x0.x; s += d0 * d0;
    double d1 = (double)e0.y - (double)x0.y; s += d1 * d1;
    double d2 = (double)e0.z - (double)x0.z; s += d2 * d2;
    double d3 = (double)e0.w - (double)x0.w; s += d3 * d3;
    double d4 = (double)e1.x - (double)x1.x; s += d4 * d4;
    double d5 = (double)e1.y - (double)x1.y; s += d5 * d5;
    double d6 = (double)e1.z - (double)x1.z; s += d6 * d6;
    double d7 = (double)e1.w - (double)x1.w; s += d7 * d7;
    a[c] = s;
  }
#pragma unroll
  for (int c = 0; c < 8; ++c)
#pragma unroll
    for (int off = 32; off; off >>= 1) a[c] += __shfl_down(a[c], off);
  int best = 0;
  if (lane == 0) {
    double d[8]; int id[8];
#pragma unroll
    for (int c = 0; c < 8; ++c) { d[c] = a[c]; id[c] = ci[c]; }
    for (int i = 0; i < 8; ++i)
      for (int j = i + 1; j < 8; ++j)
        if (d[j] < d[i] || (d[j] == d[i] && id[j] < id[i])) {
          double dt = d[i]; d[i] = d[j]; d[j] = dt;
          int it = id[i]; id[i] = id[j]; id[j] = it;
        }
    bs1[w] = d[0];   // SSE to nearest
    bs3[w] = d[2];   // SSE to third
    best = id[0];
  }
  best = __shfl(best, 0);
  const float* er = E + (size_t)best * KD;
  *(float4*)(outF + (size_t)row * KD + lane * 8) = *(const float4*)(er + lane * 8);
  *(float4*)(outF + (size_t)row * KD + lane * 8 + 4) = *(const float4*)(er + lane * 8 + 4);
  __syncthreads();
  if (threadIdx.x == 0) {
    part[blockIdx.x * 2] = bs1[0] + bs1[1] + bs1[2] + bs1[3];
    part[blockIdx.x * 2 + 1] = bs3[0] + bs3[1] + bs3[2] + bs3[3];
  }
}

// ---------------------------------------------------------------------------
// Fused merge+refine (cand in ws; no overwrite hazard with outF).
__global__ __launch_bounds__(256) void k_mrf(const float* __restrict__ X,
                                             const float* __restrict__ E,
                                             const ull* __restrict__ cand,
                                             float* __restrict__ outF,
                                             double* __restrict__ part) {
  const int lane = threadIdx.x & 63;
  const int row = blockIdx.x * 4 + (threadIdx.x >> 6);
  ull k = cand[(size_t)row * 64 + lane];
#pragma unroll
  for (int kk = 2; kk <= 64; kk <<= 1) {
#pragma unroll
    for (int j = kk >> 1; j > 0; j >>= 1) {
      ull o = __shfl_xor(k, j, 64);
      bool dirUp = (lane & kk) == 0;
      bool lower = (lane & j) == 0;
      bool pl = o < k;
      bool take = (dirUp == lower) ? pl : !pl;
      if (take) k = o;
    }
  }
  int ci[8];
#pragma unroll
  for (int c = 0; c < 8; ++c) ci[c] = (int)(__shfl(k, c, 64) & 0xffffffffull);
  refine_core(X, E, ci, row, outF, part);
}

// ---------------------------------------------------------------------------
// K_fin: one block, deterministic reduction of 3264 partial pairs -> outputs.
__global__ __launch_bounds__(256) void k_fin(const double* __restrict__ part,
                                             float* __restrict__ out) {
  const int tid = threadIdx.x;
  double a1 = 0.0, a3 = 0.0;
  for (int r = tid; r < NTAIL; r += 256) { a1 += part[2 * r]; a3 += part[2 * r + 1]; }
#pragma unroll
  for (int off = 32; off; off >>= 1) {
    a1 += __shfl_down(a1, off);
    a3 += __shfl_down(a3, off);
  }
  __shared__ double s1[4], s3[4];
  const int w = tid >> 6, lane = tid & 63;
  if (lane == 0) { s1[w] = a1; s3[w] = a3; }
  __syncthreads();
  if (tid == 0) {
    double S1 = s1[0] + s1[1] + s1[2] + s1[3];
    double S3 = s3[0] + s3[1] + s3[2] + s3[3];
    out[0] = (float)(1.0 - sqrt(S1 / S3));   // cp_score
    out[1] = (float)(0.25 * S1 / NELEM);     // k_loss
  }
}

// ---------------------------------------------------------------------------
// Fallback pair (cand in d_out tail): separate merge, then refine.
__global__ __launch_bounds__(256) void k_merge(const ull* __restrict__ cand,
                                               int* __restrict__ top8) {
  const int lane = threadIdx.x & 63;
  const int row = blockIdx.x * 4 + (threadIdx.x >> 6);
  ull k = cand[(size_t)row * 64 + lane];
#pragma unroll
  for (int kk = 2; kk <= 64; kk <<= 1) {
#pragma unroll
    for (int j = kk >> 1; j > 0; j >>= 1) {
      ull o = __shfl_xor(k, j, 64);
      bool dirUp = (lane & kk) == 0;
      bool lower = (lane & j) == 0;
      bool pl = o < k;
      bool take = (dirUp == lower) ? pl : !pl;
      if (take) k = o;
    }
  }
  if (lane < 8) top8[(size_t)row * 8 + lane] = (int)(k & 0xffffffffull);
}

__global__ __launch_bounds__(256) void k_refine_fb(const float* __restrict__ X,
                                                   const float* __restrict__ E,
                                                   const int* __restrict__ top8,
                                                   float* __restrict__ outF,
                                                   double* __restrict__ part) {
  const int row = blockIdx.x * 4 + (threadIdx.x >> 6);
  int ci[8];
#pragma unroll
  for (int c = 0; c < 8; ++c) ci[c] = top8[(size_t)row * 8 + c];
  refine_core(X, E, ci, row, outF, part);
}

// ---------------------------------------------------------------------------
extern "C" void kernel_launch(void* const* d_in, const int* in_sizes, int n_in,
                              void* d_out, int out_size, void* d_ws, size_t ws_size,
                              hipStream_t stream) {
  const float* IP = (const float*)d_in[0];   // (256,51,512) fp32
  const float* EMB = (const float*)d_in[1];  // (2048,512) fp32
  float* out = (float*)d_out;

  // ws layout (16B-aligned): EN | part | top8 | Xh | Xl | Eh | El [| cand]
  char* ws = (char*)d_ws;
  size_t off = 0;
  float* EN = (float*)(ws + off);        off += NE * 4;
  double* part = (double*)(ws + off);    off += (size_t)NTAIL * 2 * 8;  // 52 KB
  int* top8 = (int*)(ws + off);          off += (size_t)RM * 8 * 4;
  unsigned short* Xh = (unsigned short*)(ws + off); off += (size_t)RM * KD * 2;
  unsigned short* Xl = (unsigned short*)(ws + off); off += (size_t)RM * KD * 2;
  unsigned short* Ehs = (unsigned short*)(ws + off); off += (size_t)NE * KD * 2;
  unsigned short* Els = (unsigned short*)(ws + off); off += (size_t)NE * KD * 2;
  ull* candWs = (ull*)(ws + off);        off += (size_t)RM * 64 * 8;  // +6.7 MB
  const bool fused = ws_size >= off;     // ~37 MiB for the fused path

  // fallback: cand lives in d_out tail (consumed by k_merge before outF writes)
  ull* cand = fused ? candWs : (ull*)(out + 2);

  hipLaunchKernelGGL(k_prep, dim3(XB + EB + NB), dim3(256), 0, stream,
                     IP, EMB, Xh, Xl, Ehs, Els, EN);
  hipLaunchKernelGGL(k_dist_bf16, dim3(RM / BM, NBLK), dim3(256), 0, stream,
                     Xh, Xl, Ehs, Els, EN, cand);
  if (fused) {
    hipLaunchKernelGGL(k_mrf, dim3(NTAIL), dim3(256), 0, stream,
                       IP, EMB, cand, out + 2, part);
  } else {
    hipLaunchKernelGGL(k_merge, dim3(NTAIL), dim3(256), 0, stream, cand, top8);
    hipLaunchKernelGGL(k_refine_fb, dim3(NTAIL), dim3(256), 0, stream,
                       IP, EMB, top8, out + 2, part);
  }
  hipLaunchKernelGGL(k_fin, dim3(1), dim3(256), 0, stream, part, out);
}

// Round 9
// 216.353 us; speedup vs baseline: 1.7696x; 1.1338x over previous
//
#include <hip/hip_runtime.h>
#include <hip/hip_bf16.h>
#include <math.h>

// Problem constants
#define RM 13056         // 256*17*3 rows of flat x
#define KD 512           // feature dim
#define NE 2048          // codebook entries
#define NELEM 6684672.0  // 256*51*512 elements for the mean

// dist kernel tiling
#define BM 128
#define BN 256
#define BK 32
#define NKT (KD / BK)    // 16 k-tiles
#define NBLK (NE / BN)   // 8 n-blocks
#define NCAND (NBLK * 4) // 32 candidates/row
#define NTAIL (RM / 4)   // 3264 tail blocks (4 rows each)

typedef __attribute__((ext_vector_type(8))) short bf16x8;
typedef __attribute__((ext_vector_type(4))) float f32x4;
typedef unsigned long long ull;

// async global->LDS, 16B per lane; lds base wave-uniform, HW appends lane*16 (m104)
__device__ __forceinline__ void dma16(const void* g, void* l) {
  __builtin_amdgcn_global_load_lds((const __attribute__((address_space(1))) void*)g,
                                   (__attribute__((address_space(3))) void*)l, 16, 0, 0);
}

// order-preserving (dist, idx) -> u64 key: ascending u64 == lexicographic (d, ix)
__device__ __forceinline__ ull packdi(float d, int ix) {
  unsigned u = __float_as_uint(d);
  u ^= (unsigned)((int)u >> 31) | 0x80000000u;
  return ((ull)u << 32) | (unsigned)ix;
}

// ---------------------------------------------------------------------------
// K_prep: fused preprocessing (layout is BN-independent).
#define XB (RM * 64 / 256)   // 3264
#define EB (NE * 64 / 256)   // 512
#define NB (NE / 4)          // 512
__device__ __forceinline__ void split_chunks(const float* __restrict__ src,
                                             unsigned short* __restrict__ hi,
                                             unsigned short* __restrict__ lo,
                                             int rows, int o) {
  int t4 = o >> 2;
  int kt = t4 / rows;
  int row = t4 - kt * rows;
  int slot = o & 3;
  int q = slot ^ ((row >> 1) & 3);
  const float* s = src + (size_t)row * KD + kt * 32 + q * 8;
  float4 v0 = ((const float4*)s)[0];
  float4 v1 = ((const float4*)s)[1];
  float f[8] = {v0.x, v0.y, v0.z, v0.w, v1.x, v1.y, v1.z, v1.w};
  unsigned hh[4], ll[4];
#pragma unroll
  for (int j = 0; j < 4; ++j) {
    __hip_bfloat16 b0 = __float2bfloat16(f[2 * j]);
    __hip_bfloat16 b1 = __float2bfloat16(f[2 * j + 1]);
    __hip_bfloat16 c0 = __float2bfloat16(f[2 * j] - __bfloat162float(b0));
    __hip_bfloat16 c1 = __float2bfloat16(f[2 * j + 1] - __bfloat162float(b1));
    hh[j] = (unsigned)*(unsigned short*)&b0 | ((unsigned)*(unsigned short*)&b1 << 16);
    ll[j] = (unsigned)*(unsigned short*)&c0 | ((unsigned)*(unsigned short*)&c1 << 16);
  }
  ((uint4*)hi)[o] = make_uint4(hh[0], hh[1], hh[2], hh[3]);
  ((uint4*)lo)[o] = make_uint4(ll[0], ll[1], ll[2], ll[3]);
}

__global__ __launch_bounds__(256) void k_prep(const float* __restrict__ X,
                                              const float* __restrict__ E,
                                              unsigned short* __restrict__ Xh,
                                              unsigned short* __restrict__ Xl,
                                              unsigned short* __restrict__ Eh,
                                              unsigned short* __restrict__ El,
                                              float* __restrict__ EN) {
  const int b = blockIdx.x, tid = threadIdx.x;
  if (b < XB) {
    split_chunks(X, Xh, Xl, RM, b * 256 + tid);
  } else if (b < XB + EB) {
    split_chunks(E, Eh, El, NE, (b - XB) * 256 + tid);
  } else {
    int n = (b - XB - EB) * 4 + (tid >> 6);
    int lane = tid & 63;
    const float* e = E + (size_t)n * KD;
    float s = 0.f;
#pragma unroll
    for (int j = 0; j < 8; ++j) { float v = e[lane + 64 * j]; s += v * v; }
#pragma unroll
    for (int off = 32; off; off >>= 1) s += __shfl_down(s, off);
    if (lane == 0) EN[n] = s;
  }
}

// ---------------------------------------------------------------------------
// LDS chunk addressing (ushort elem offset): chunk q of local row at slot
// q ^ ((row>>1)&3). Conflicts measured 0 (rounds 4-8).
__device__ __forceinline__ int chidx(int row, int q) {
  return (row * 4 + (q ^ ((row >> 1) & 3))) * 8;
}

// K1: split-bf16 MFMA distance tile, BM=128 x BN=256 per block.
// grid (102,8), block 256 = 4 waves; wave w owns rows [w*32,+32) x all 256 cols.
// Per kt per wave: 96 MFMA, 36 ds_read_b128, 12 contiguous-1KiB DMA.
// launch_bounds (256,2): 256-VGPR budget, no spill (acc alone is 128).
__global__ __launch_bounds__(256, 2) void k_dist_bf16(
    const unsigned short* __restrict__ Xh, const unsigned short* __restrict__ Xl,
    const unsigned short* __restrict__ Eh, const unsigned short* __restrict__ El,
    const float* __restrict__ EN, ull* __restrict__ cand) {
  __shared__ __align__(16) unsigned short sXh[BM * BK], sXl[BM * BK];
  __shared__ __align__(16) unsigned short sEh[BN * BK], sEl[BN * BK];
  __shared__ float sEN[BN];

  const int tid = threadIdx.x;
  const int lane = tid & 63;
  const int w = tid >> 6;
  const int quad = lane >> 4;
  const int lx = lane & 15;
  const int rowBase = blockIdx.x * BM;
  const int colBase = blockIdx.y * BN;

  sEN[tid] = EN[colBase + tid];

  // frag LDS offsets (constant per lane)
  int aidx[2], bidx[16];
#pragma unroll
  for (int mt = 0; mt < 2; ++mt) aidx[mt] = chidx(w * 32 + mt * 16 + lx, quad);
#pragma unroll
  for (int ct = 0; ct < 16; ++ct) bidx[ct] = chidx(ct * 16 + lx, quad);

  f32x4 acc[2][16];
#pragma unroll
  for (int mt = 0; mt < 2; ++mt)
#pragma unroll
    for (int ct = 0; ct < 16; ++ct) acc[mt][ct] = (f32x4){0.f, 0.f, 0.f, 0.f};

  for (int kt = 0; kt < NKT; ++kt) {
    const size_t xbase = ((size_t)kt * RM + rowBase) * 4;   // chunk units
    const size_t ebase = ((size_t)kt * NE + colBase) * 4;
    __syncthreads();  // previous tile's readers done
#pragma unroll
    for (int i = 0; i < 2; ++i) {   // X: 512 chunks
      const int c = i * 256 + tid;
      const int ldsOff = (i * 256 + w * 64) * 8;
      dma16(Xh + (xbase + c) * 8, &sXh[ldsOff]);
      dma16(Xl + (xbase + c) * 8, &sXl[ldsOff]);
    }
#pragma unroll
    for (int i = 0; i < 4; ++i) {   // E: 1024 chunks
      const int c = i * 256 + tid;
      const int ldsOff = (i * 256 + w * 64) * 8;
      dma16(Eh + (ebase + c) * 8, &sEh[ldsOff]);
      dma16(El + (ebase + c) * 8, &sEl[ldsOff]);
    }
    __syncthreads();  // compiler drains vmcnt before barrier

    bf16x8 Ah[2], Al[2];
#pragma unroll
    for (int mt = 0; mt < 2; ++mt) {
      Ah[mt] = *(const bf16x8*)&sXh[aidx[mt]];
      Al[mt] = *(const bf16x8*)&sXl[aidx[mt]];
    }
#pragma unroll
    for (int ct = 0; ct < 16; ++ct) {
      bf16x8 Bh = *(const bf16x8*)&sEh[bidx[ct]];
      bf16x8 Bl = *(const bf16x8*)&sEl[bidx[ct]];
#pragma unroll
      for (int mt = 0; mt < 2; ++mt) {
        acc[mt][ct] = __builtin_amdgcn_mfma_f32_16x16x32_bf16(Ah[mt], Bh, acc[mt][ct], 0, 0, 0);
        acc[mt][ct] = __builtin_amdgcn_mfma_f32_16x16x32_bf16(Al[mt], Bh, acc[mt][ct], 0, 0, 0);
        acc[mt][ct] = __builtin_amdgcn_mfma_f32_16x16x32_bf16(Ah[mt], Bl, acc[mt][ct], 0, 0, 0);
      }
    }
  }

  // epilogue: C/D layout col=lane&15, row=quad*4+reg (m89/m91)
  float en[16];
#pragma unroll
  for (int ct = 0; ct < 16; ++ct) en[ct] = sEN[ct * 16 + lx];

#pragma unroll
  for (int mt = 0; mt < 2; ++mt) {
#pragma unroll
    for (int j = 0; j < 4; ++j) {
      float a0 = 3.4e38f, a1 = 3.4e38f, a2 = 3.4e38f, a3 = 3.4e38f;
      int i0 = 0x7fffffff, i1 = i0, i2 = i0, i3 = i0;
#pragma unroll
      for (int ct = 0; ct < 16; ++ct) {
        float d = en[ct] - 2.0f * acc[mt][ct][j];
        int ix = colBase + ct * 16 + lx;
        // ascending idx + strict < keeps the lower index on ties
        if (d < a3) {
          if (d < a2) { a3 = a2; i3 = i2;
            if (d < a1) { a2 = a1; i2 = i1;
              if (d < a0) { a1 = a0; i1 = i0; a0 = d; i0 = ix; }
              else { a1 = d; i1 = ix; } }
            else { a2 = d; i2 = ix; } }
          else { a3 = d; i3 = ix; }
        }
      }
      // 4-round min-extraction across the 16-lane group (keys unique per row)
      ull k0 = packdi(a0, i0), k1 = packdi(a1, i1);
      ull k2 = packdi(a2, i2), k3 = packdi(a3, i3);
      int pos = 0;
      ull res[4];
#pragma unroll
      for (int r = 0; r < 4; ++r) {
        ull h = pos == 0 ? k0 : pos == 1 ? k1 : pos == 2 ? k2 : pos == 3 ? k3 : ~0ull;
        ull m = h;
#pragma unroll
        for (int step = 1; step < 16; step <<= 1) {
          ull o = __shfl_xor(m, step, 16);
          m = o < m ? o : m;
        }
        res[r] = m;
        pos += (h == m) ? 1 : 0;
      }
      if (lx == 0) {
        int row = rowBase + w * 32 + mt * 16 + quad * 4 + j;
        ull* dst = cand + (size_t)row * NCAND + blockIdx.y * 4;
        dst[0] = res[0]; dst[1] = res[1]; dst[2] = res[2]; dst[3] = res[3];
      }
    }
  }
}

// ---------------------------------------------------------------------------
// Shared tail core: fp64 refine of ci[8] for `row` (one wave), then exact
// per-block (S1,S3) partials via PLAIN stores (no atomics, no fences).
__device__ __forceinline__ void refine_core(const float* __restrict__ X,
                                            const float* __restrict__ E,
                                            const int* ci, int row,
                                            float* __restrict__ outF,
                                            double* __restrict__ part) {
  const int w = threadIdx.x >> 6, lane = threadIdx.x & 63;
  __shared__ double bs1[4], bs3[4];
  const float* xr = X + (size_t)row * KD;
  float4 x0 = *(const float4*)(xr + lane * 8);
  float4 x1 = *(const float4*)(xr + lane * 8 + 4);
  double a[8];
#pragma unroll
  for (int c = 0; c < 8; ++c) {
    const float* er = E + (size_t)ci[c] * KD;
    float4 e0 = *(const float4*)(er + lane * 8);
    float4 e1 = *(const float4*)(er + lane * 8 + 4);
    double s = 0.0;
    double d0 = (double)e0.x - (double)x0.x; s += d0 * d0;
    double d1 = (double)e0.y - (double)x0.y; s += d1 * d1;
    double d2 = (double)e0.z - (double)x0.z; s += d2 * d2;
    double d3 = (double)e0.w - (double)x0.w; s += d3 * d3;
    double d4 = (double)e1.x - (double)x1.x; s += d4 * d4;
    double d5 = (double)e1.y - (double)x1.y; s += d5 * d5;
    double d6 = (double)e1.z - (double)x1.z; s += d6 * d6;
    double d7 = (double)e1.w - (double)x1.w; s += d7 * d7;
    a[c] = s;
  }
#pragma unroll
  for (int c = 0; c < 8; ++c)
#pragma unroll
    for (int off = 32; off; off >>= 1) a[c] += __shfl_down(a[c], off);
  int best = 0;
  if (lane == 0) {
    double d[8]; int id[8];
#pragma unroll
    for (int c = 0; c < 8; ++c) { d[c] = a[c]; id[c] = ci[c]; }
    for (int i = 0; i < 8; ++i)
      for (int j = i + 1; j < 8; ++j)
        if (d[j] < d[i] || (d[j] == d[i] && id[j] < id[i])) {
          double dt = d[i]; d[i] = d[j]; d[j] = dt;
          int it = id[i]; id[i] = id[j]; id[j] = it;
        }
    bs1[w] = d[0];   // SSE to nearest
    bs3[w] = d[2];   // SSE to third
    best = id[0];
  }
  best = __shfl(best, 0);
  const float* er = E + (size_t)best * KD;
  *(float4*)(outF + (size_t)row * KD + lane * 8) = *(const float4*)(er + lane * 8);
  *(float4*)(outF + (size_t)row * KD + lane * 8 + 4) = *(const float4*)(er + lane * 8 + 4);
  __syncthreads();
  if (threadIdx.x == 0) {
    part[blockIdx.x * 2] = bs1[0] + bs1[1] + bs1[2] + bs1[3];
    part[blockIdx.x * 2 + 1] = bs3[0] + bs3[1] + bs3[2] + bs3[3];
  }
}

// 64-lane bitonic sort of a key (lanes >= NCAND carry ~0 pads)
__device__ __forceinline__ ull sort64(ull k, int lane) {
#pragma unroll
  for (int kk = 2; kk <= 64; kk <<= 1) {
#pragma unroll
    for (int j = kk >> 1; j > 0; j >>= 1) {
      ull o = __shfl_xor(k, j, 64);
      bool dirUp = (lane & kk) == 0;
      bool lower = (lane & j) == 0;
      bool pl = o < k;
      bool take = (dirUp == lower) ? pl : !pl;
      if (take) k = o;
    }
  }
  return k;
}

// ---------------------------------------------------------------------------
// Fused merge+refine (cand in ws; no overwrite hazard with outF).
__global__ __launch_bounds__(256) void k_mrf(const float* __restrict__ X,
                                             const float* __restrict__ E,
                                             const ull* __restrict__ cand,
                                             float* __restrict__ outF,
                                             double* __restrict__ part) {
  const int lane = threadIdx.x & 63;
  const int row = blockIdx.x * 4 + (threadIdx.x >> 6);
  ull k = lane < NCAND ? cand[(size_t)row * NCAND + lane] : ~0ull;
  k = sort64(k, lane);
  int ci[8];
#pragma unroll
  for (int c = 0; c < 8; ++c) ci[c] = (int)(__shfl(k, c, 64) & 0xffffffffull);
  refine_core(X, E, ci, row, outF, part);
}

// ---------------------------------------------------------------------------
// K_fin: one block, deterministic reduction of 3264 partial pairs -> outputs.
__global__ __launch_bounds__(256) void k_fin(const double* __restrict__ part,
                                             float* __restrict__ out) {
  const int tid = threadIdx.x;
  double a1 = 0.0, a3 = 0.0;
  for (int r = tid; r < NTAIL; r += 256) { a1 += part[2 * r]; a3 += part[2 * r + 1]; }
#pragma unroll
  for (int off = 32; off; off >>= 1) {
    a1 += __shfl_down(a1, off);
    a3 += __shfl_down(a3, off);
  }
  __shared__ double s1[4], s3[4];
  const int w = tid >> 6, lane = tid & 63;
  if (lane == 0) { s1[w] = a1; s3[w] = a3; }
  __syncthreads();
  if (tid == 0) {
    double S1 = s1[0] + s1[1] + s1[2] + s1[3];
    double S3 = s3[0] + s3[1] + s3[2] + s3[3];
    out[0] = (float)(1.0 - sqrt(S1 / S3));   // cp_score
    out[1] = (float)(0.25 * S1 / NELEM);     // k_loss
  }
}

// ---------------------------------------------------------------------------
// Fallback pair (cand in d_out tail): separate merge, then refine.
__global__ __launch_bounds__(256) void k_merge(const ull* __restrict__ cand,
                                               int* __restrict__ top8) {
  const int lane = threadIdx.x & 63;
  const int row = blockIdx.x * 4 + (threadIdx.x >> 6);
  ull k = lane < NCAND ? cand[(size_t)row * NCAND + lane] : ~0ull;
  k = sort64(k, lane);
  if (lane < 8) top8[(size_t)row * 8 + lane] = (int)(k & 0xffffffffull);
}

__global__ __launch_bounds__(256) void k_refine_fb(const float* __restrict__ X,
                                                   const float* __restrict__ E,
                                                   const int* __restrict__ top8,
                                                   float* __restrict__ outF,
                                                   double* __restrict__ part) {
  const int row = blockIdx.x * 4 + (threadIdx.x >> 6);
  int ci[8];
#pragma unroll
  for (int c = 0; c < 8; ++c) ci[c] = top8[(size_t)row * 8 + c];
  refine_core(X, E, ci, row, outF, part);
}

// ---------------------------------------------------------------------------
extern "C" void kernel_launch(void* const* d_in, const int* in_sizes, int n_in,
                              void* d_out, int out_size, void* d_ws, size_t ws_size,
                              hipStream_t stream) {
  const float* IP = (const float*)d_in[0];   // (256,51,512) fp32
  const float* EMB = (const float*)d_in[1];  // (2048,512) fp32
  float* out = (float*)d_out;

  // ws layout (16B-aligned): EN | part | top8 | Xh | Xl | Eh | El [| cand]
  char* ws = (char*)d_ws;
  size_t off = 0;
  float* EN = (float*)(ws + off);        off += NE * 4;
  double* part = (double*)(ws + off);    off += (size_t)NTAIL * 2 * 8;  // 52 KB
  int* top8 = (int*)(ws + off);          off += (size_t)RM * 8 * 4;
  unsigned short* Xh = (unsigned short*)(ws + off); off += (size_t)RM * KD * 2;
  unsigned short* Xl = (unsigned short*)(ws + off); off += (size_t)RM * KD * 2;
  unsigned short* Ehs = (unsigned short*)(ws + off); off += (size_t)NE * KD * 2;
  unsigned short* Els = (unsigned short*)(ws + off); off += (size_t)NE * KD * 2;
  ull* candWs = (ull*)(ws + off);        off += (size_t)RM * NCAND * 8;  // +3.3 MB
  const bool fused = ws_size >= off;     // ~34 MiB for the fused path

  // fallback: cand lives in d_out tail (consumed by k_merge before outF writes)
  ull* cand = fused ? candWs : (ull*)(out + 2);

  hipLaunchKernelGGL(k_prep, dim3(XB + EB + NB), dim3(256), 0, stream,
                     IP, EMB, Xh, Xl, Ehs, Els, EN);
  hipLaunchKernelGGL(k_dist_bf16, dim3(RM / BM, NBLK), dim3(256), 0, stream,
                     Xh, Xl, Ehs, Els, EN, cand);
  if (fused) {
    hipLaunchKernelGGL(k_mrf, dim3(NTAIL), dim3(256), 0, stream,
                       IP, EMB, cand, out + 2, part);
  } else {
    hipLaunchKernelGGL(k_merge, dim3(NTAIL), dim3(256), 0, stream, cand, top8);
    hipLaunchKernelGGL(k_refine_fb, dim3(NTAIL), dim3(256), 0, stream,
                       IP, EMB, top8, out + 2, part);
  }
  hipLaunchKernelGGL(k_fin, dim3(1), dim3(256), 0, stream, part, out);
}